// Round 9
// baseline (62.732 us; speedup 1.0000x reference)
//
#include <hip/hip_runtime.h>

// RBF kernel matrix: out[r,i,j] = os^2 * exp(-0.5 * ||(x1_i - x2_j)/ls||^2)
// R=4, N1=N2=4096, D=8. Output 268 MB fp32 -> write-BW bound.
// Evidence: occupancy optimum at 16 waves/CU (8->55, 16->47.3, 24->51, 32->56).
// Residual 5.66 vs 7.1 TB/s gap attributed to write-STREAM topology: R5 had
// 4096 scattered 2KB streams; fill has few giant sequential streams.
// R8: 512-thread block = 8 waves x 512-j register panels = one full 16KB row
// per row-step; block sweeps 32 rows -> contiguous 512KB region; 2 blocks/CU
// -> 2 fill-like streams/CU at unchanged 16 waves/CU and unchanged inner loop.

constexpr int D   = 8;
constexpr int JW  = 512;   // j-span per wave
constexpr int CH  = 2;     // chunks of 256 j per wave (64 lanes x 4)
constexpr int SEG = 32;    // consecutive rows per block

#if __has_builtin(__builtin_amdgcn_exp2f)
#define FAST_EXP2(x) __builtin_amdgcn_exp2f(x)
#else
#define FAST_EXP2(x) __expf((x) * 0.69314718f)   // exp(x*ln2) == 2^x
#endif

__global__ __launch_bounds__(512, 4) void rbf_kernel(
    const float* __restrict__ x1, const float* __restrict__ x2,
    const float* __restrict__ ls, const float* __restrict__ osc,
    float* __restrict__ out, int N1, int N2)
{
    const int tid  = threadIdx.x;
    const int lane = tid & 63;
    const int wv   = tid >> 6;              // [0,8)
    const int r    = blockIdx.y;
    const int row0 = blockIdx.x * SEG;

    constexpr float L2E  = 1.44269504f;   //  log2(e)
    constexpr float NH2E = -0.72134752f;  // -0.5*log2(e)

    float4 l0 = *reinterpret_cast<const float4*>(ls);
    float4 l1 = *reinterpret_cast<const float4*>(ls + 4);
    float4 inv0, inv1;
    inv0.x = 1.0f/l0.x; inv0.y = 1.0f/l0.y; inv0.z = 1.0f/l0.z; inv0.w = 1.0f/l0.w;
    inv1.x = 1.0f/l1.x; inv1.y = 1.0f/l1.y; inv1.z = 1.0f/l1.z; inv1.w = 1.0f/l1.w;
    const float lg2os = __log2f(osc[0] * osc[0]);   // exact 0 for os=1

    // ---- prologue: lane's 8 x2 points (4 per chunk) -> registers, dim-major ----
    float4 bd[CH][D];   // [chunk][dim] -> float4 over the lane's 4 j-points
    float4 cb[CH];      // -0.5*log2e*||b||^2 + lg2os
#pragma unroll
    for (int c = 0; c < CH; ++c) {
        const float* bp = x2 + ((size_t)r * N2 + wv * JW + c * 256 + lane * 4) * D;
        float4 u[8];    // 4 points x 2 float4, scaled
#pragma unroll
        for (int p = 0; p < 4; ++p) {
            float4 v0 = *reinterpret_cast<const float4*>(bp + p * D);
            float4 v1 = *reinterpret_cast<const float4*>(bp + p * D + 4);
            v0.x *= inv0.x; v0.y *= inv0.y; v0.z *= inv0.z; v0.w *= inv0.w;
            v1.x *= inv1.x; v1.y *= inv1.y; v1.z *= inv1.z; v1.w *= inv1.w;
            u[2*p]   = v0;
            u[2*p+1] = v1;
        }
        // transpose point-major -> dim-major (static indices -> stays in regs)
#pragma unroll
        for (int d = 0; d < D; ++d) {
            float4 t;
            t.x = reinterpret_cast<const float*>(&u[0 + (d >> 2)])[d & 3];
            t.y = reinterpret_cast<const float*>(&u[2 + (d >> 2)])[d & 3];
            t.z = reinterpret_cast<const float*>(&u[4 + (d >> 2)])[d & 3];
            t.w = reinterpret_cast<const float*>(&u[6 + (d >> 2)])[d & 3];
            bd[c][d] = t;
        }
        float4 t;
        t.x = u[0].x*u[0].x + u[0].y*u[0].y + u[0].z*u[0].z + u[0].w*u[0].w
            + u[1].x*u[1].x + u[1].y*u[1].y + u[1].z*u[1].z + u[1].w*u[1].w;
        t.y = u[2].x*u[2].x + u[2].y*u[2].y + u[2].z*u[2].z + u[2].w*u[2].w
            + u[3].x*u[3].x + u[3].y*u[3].y + u[3].z*u[3].z + u[3].w*u[3].w;
        t.z = u[4].x*u[4].x + u[4].y*u[4].y + u[4].z*u[4].z + u[4].w*u[4].w
            + u[5].x*u[5].x + u[5].y*u[5].y + u[5].z*u[5].z + u[5].w*u[5].w;
        t.w = u[6].x*u[6].x + u[6].y*u[6].y + u[6].z*u[6].z + u[6].w*u[6].w
            + u[7].x*u[7].x + u[7].y*u[7].y + u[7].z*u[7].z + u[7].w*u[7].w;
        cb[c].x = fmaf(t.x, NH2E, lg2os);
        cb[c].y = fmaf(t.y, NH2E, lg2os);
        cb[c].z = fmaf(t.z, NH2E, lg2os);
        cb[c].w = fmaf(t.w, NH2E, lg2os);
    }

    __syncthreads();   // phase-align the 8 waves so the row's 16KB is co-written

    // ---- main loop: 32 rows; block emits one full 16KB row per step ----
    const float* xrow  = x1 + ((size_t)r * N1 + row0) * D;
    float*       obase = out + ((size_t)r * N1 + row0) * (size_t)N2
                             + wv * JW + lane * 4;

#pragma unroll 4
    for (int s = 0; s < SEG; ++s) {
        float4 u0 = *reinterpret_cast<const float4*>(xrow + (size_t)s * D);
        float4 u1 = *reinterpret_cast<const float4*>(xrow + (size_t)s * D + 4);
        float a[D];
        a[0] = u0.x * inv0.x; a[1] = u0.y * inv0.y;
        a[2] = u0.z * inv0.z; a[3] = u0.w * inv0.w;
        a[4] = u1.x * inv1.x; a[5] = u1.y * inv1.y;
        a[6] = u1.z * inv1.z; a[7] = u1.w * inv1.w;
        float asq = 0.f;
#pragma unroll
        for (int d = 0; d < D; ++d) asq = fmaf(a[d], a[d], asq);
        const float ca = asq * NH2E;

        float* op = obase + (size_t)s * N2;
#pragma unroll
        for (int c = 0; c < CH; ++c) {
            float p0 = 0.f, p1 = 0.f, p2 = 0.f, p3 = 0.f;
#pragma unroll
            for (int d = 0; d < D; ++d) {
                const float av = a[d];
                p0 = fmaf(av, bd[c][d].x, p0);
                p1 = fmaf(av, bd[c][d].y, p1);
                p2 = fmaf(av, bd[c][d].z, p2);
                p3 = fmaf(av, bd[c][d].w, p3);
            }
            float4 o;
            o.x = FAST_EXP2(fmaf(p0, L2E, ca + cb[c].x));
            o.y = FAST_EXP2(fmaf(p1, L2E, ca + cb[c].y));
            o.z = FAST_EXP2(fmaf(p2, L2E, ca + cb[c].z));
            o.w = FAST_EXP2(fmaf(p3, L2E, ca + cb[c].w));
            *reinterpret_cast<float4*>(op + c * 256) = o;
        }
    }
}

extern "C" void kernel_launch(void* const* d_in, const int* in_sizes, int n_in,
                              void* d_out, int out_size, void* d_ws, size_t ws_size,
                              hipStream_t stream) {
    (void)in_sizes; (void)n_in; (void)d_ws; (void)ws_size; (void)out_size;
    const float* x1  = (const float*)d_in[0];
    const float* x2  = (const float*)d_in[1];
    const float* ls  = (const float*)d_in[2];
    const float* osc = (const float*)d_in[3];
    float* out = (float*)d_out;

    const int N1 = 4096, N2 = 4096;
    dim3 grid(N1 / SEG, 4);   // 128 row-tiles x 4 r = 512 blocks (2 per CU)
    rbf_kernel<<<grid, dim3(512), 0, stream>>>(x1, x2, ls, osc, out, N1, N2);
}

// Round 10
// 47.168 us; speedup vs baseline: 1.3300x; 1.3300x over previous
//
#include <hip/hip_runtime.h>

// RBF kernel matrix: out[r,i,j] = os^2 * exp(-0.5 * ||(x1_i - x2_j)/ls||^2)
// R=4, N1=N2=4096, D=8. Output 268 MB fp32 -> write-BW bound.
// BEST CONFIG (R5, 47.33 us = 5.67 TB/s effective ~ 90% of achievable):
// 16 waves/CU, 2 KB contiguous store runs, x2 tile staged once per block,
// barrier-free steady loop with wave-uniform x1 loads. Probed and rejected:
// run length 256B/1KB/4KB, occupancy 8/24/32 waves, nt-stores, stream
// co-location (all regressed or flat). This is the practical write ceiling.

constexpr int D  = 8;
constexpr int BI = 32;    // rows per i-subtile (8 per wave)
constexpr int IT = 4;     // i-subtiles per block -> 128 rows/block
constexpr int BJ = 512;   // x2 cols per block (2 chunks of 4 per lane)

#if __has_builtin(__builtin_amdgcn_exp2f)
#define FAST_EXP2(x) __builtin_amdgcn_exp2f(x)
#else
#define FAST_EXP2(x) __expf((x) * 0.69314718f)   // exp(x*ln2) == 2^x
#endif

__global__ __launch_bounds__(256, 4) void rbf_kernel(
    const float* __restrict__ x1, const float* __restrict__ x2,
    const float* __restrict__ ls, const float* __restrict__ osc,
    float* __restrict__ out, int N1, int N2)
{
    __shared__ float sb[D][BJ];   // x2 tile, scaled, d-major  (16 KB)
    __shared__ float sbb[BJ];     // ||b||^2 per j             (2 KB)

    const int r   = blockIdx.z;
    const int i0  = blockIdx.y * (BI * IT);
    const int j0  = blockIdx.x * BJ;
    const int tid = threadIdx.x;

    float4 l0 = *reinterpret_cast<const float4*>(ls);
    float4 l1 = *reinterpret_cast<const float4*>(ls + 4);
    float4 inv0, inv1;
    inv0.x = 1.0f / l0.x; inv0.y = 1.0f / l0.y; inv0.z = 1.0f / l0.z; inv0.w = 1.0f / l0.w;
    inv1.x = 1.0f / l1.x; inv1.y = 1.0f / l1.y; inv1.z = 1.0f / l1.z; inv1.w = 1.0f / l1.w;

    // ---- stage x2: 2 points per thread (wave reads 2 KB contiguous per pass) ----
#pragma unroll
    for (int k = 0; k < 2; ++k) {
        const int p = k * 256 + tid;
        const float* src = x2 + ((size_t)r * N2 + j0 + p) * D;
        float4 v0 = *reinterpret_cast<const float4*>(src);
        float4 v1 = *reinterpret_cast<const float4*>(src + 4);
        v0.x *= inv0.x; v0.y *= inv0.y; v0.z *= inv0.z; v0.w *= inv0.w;
        v1.x *= inv1.x; v1.y *= inv1.y; v1.z *= inv1.z; v1.w *= inv1.w;
        sb[0][p] = v0.x; sb[1][p] = v0.y; sb[2][p] = v0.z; sb[3][p] = v0.w;
        sb[4][p] = v1.x; sb[5][p] = v1.y; sb[6][p] = v1.z; sb[7][p] = v1.w;
        sbb[p] = v0.x*v0.x + v0.y*v0.y + v0.z*v0.z + v0.w*v0.w
               + v1.x*v1.x + v1.y*v1.y + v1.z*v1.z + v1.w*v1.w;
    }
    const float os2   = osc[0] * osc[0];
    const float lg2os = __log2f(os2);     // os2*2^t == 2^(t+lg2os); exact 0 for os=1
    __syncthreads();                      // the ONLY barrier in the kernel

    // ---- per-lane j-state (register-resident for the whole block) ----
    const int lane = tid & 63;
    const int wv   = tid >> 6;

    float4 bd0[D], bd1[D];
#pragma unroll
    for (int d = 0; d < D; ++d) {
        bd0[d] = *reinterpret_cast<const float4*>(&sb[d][lane * 4]);
        bd1[d] = *reinterpret_cast<const float4*>(&sb[d][256 + lane * 4]);
    }
    const float4 bbA = *reinterpret_cast<const float4*>(&sbb[lane * 4]);
    const float4 bbB = *reinterpret_cast<const float4*>(&sbb[256 + lane * 4]);

    constexpr float L2E  = 1.44269504f;   //  log2(e)
    constexpr float NH2E = -0.72134752f;  // -0.5*log2(e)

    float4 cb0, cb1;   // -0.5*log2e*bb + log2(os^2)
    cb0.x = fmaf(bbA.x, NH2E, lg2os); cb0.y = fmaf(bbA.y, NH2E, lg2os);
    cb0.z = fmaf(bbA.z, NH2E, lg2os); cb0.w = fmaf(bbA.w, NH2E, lg2os);
    cb1.x = fmaf(bbB.x, NH2E, lg2os); cb1.y = fmaf(bbB.y, NH2E, lg2os);
    cb1.z = fmaf(bbB.z, NH2E, lg2os); cb1.w = fmaf(bbB.w, NH2E, lg2os);

    float* obase = out + ((size_t)r * N1 + i0) * (size_t)N2 + j0 + lane * 4;
    const float* x1base = x1 + ((size_t)r * N1 + i0) * D;

    // ---- steady loop: 32 rows per wave, no barriers, uniform x1 loads ----
#pragma unroll 4
    for (int t = 0; t < IT; ++t) {
#pragma unroll
        for (int ii = 0; ii < 8; ++ii) {
            const int row = t * BI + wv * 8 + ii;
            // wave-uniform address -> scalar loads from L2-resident x1
            const float* xp = x1base + (size_t)row * D;
            float a[D];
            float asq = 0.f;
            {
                const float4 u0 = *reinterpret_cast<const float4*>(xp);
                const float4 u1 = *reinterpret_cast<const float4*>(xp + 4);
                a[0] = u0.x * inv0.x; a[1] = u0.y * inv0.y;
                a[2] = u0.z * inv0.z; a[3] = u0.w * inv0.w;
                a[4] = u1.x * inv1.x; a[5] = u1.y * inv1.y;
                a[6] = u1.z * inv1.z; a[7] = u1.w * inv1.w;
#pragma unroll
                for (int d = 0; d < D; ++d) asq = fmaf(a[d], a[d], asq);
            }
            const float ca = asq * NH2E;

            float p0 = 0.f, p1 = 0.f, p2 = 0.f, p3 = 0.f;
            float q0 = 0.f, q1 = 0.f, q2 = 0.f, q3 = 0.f;
#pragma unroll
            for (int d = 0; d < D; ++d) {
                const float av = a[d];
                p0 = fmaf(av, bd0[d].x, p0);
                p1 = fmaf(av, bd0[d].y, p1);
                p2 = fmaf(av, bd0[d].z, p2);
                p3 = fmaf(av, bd0[d].w, p3);
                q0 = fmaf(av, bd1[d].x, q0);
                q1 = fmaf(av, bd1[d].y, q1);
                q2 = fmaf(av, bd1[d].z, q2);
                q3 = fmaf(av, bd1[d].w, q3);
            }
            float4 oA, oB;
            oA.x = FAST_EXP2(fmaf(p0, L2E, ca + cb0.x));
            oA.y = FAST_EXP2(fmaf(p1, L2E, ca + cb0.y));
            oA.z = FAST_EXP2(fmaf(p2, L2E, ca + cb0.z));
            oA.w = FAST_EXP2(fmaf(p3, L2E, ca + cb0.w));
            oB.x = FAST_EXP2(fmaf(q0, L2E, ca + cb1.x));
            oB.y = FAST_EXP2(fmaf(q1, L2E, ca + cb1.y));
            oB.z = FAST_EXP2(fmaf(q2, L2E, ca + cb1.z));
            oB.w = FAST_EXP2(fmaf(q3, L2E, ca + cb1.w));
            float* op = obase + (size_t)row * N2;
            *reinterpret_cast<float4*>(op)       = oA;
            *reinterpret_cast<float4*>(op + 256) = oB;
        }
    }
}

extern "C" void kernel_launch(void* const* d_in, const int* in_sizes, int n_in,
                              void* d_out, int out_size, void* d_ws, size_t ws_size,
                              hipStream_t stream) {
    (void)in_sizes; (void)n_in; (void)d_ws; (void)ws_size; (void)out_size;
    const float* x1  = (const float*)d_in[0];
    const float* x2  = (const float*)d_in[1];
    const float* ls  = (const float*)d_in[2];
    const float* osc = (const float*)d_in[3];
    float* out = (float*)d_out;

    const int R = 4, N1 = 4096, N2 = 4096;
    dim3 grid(N2 / BJ, N1 / (BI * IT), R);
    rbf_kernel<<<grid, dim3(256), 0, stream>>>(x1, x2, ls, osc, out, N1, N2);
}